// Round 1
// baseline (282.101 us; speedup 1.0000x reference)
//
#include <hip/hip_runtime.h>
#include <math.h>

// Problem constants (from reference): B=8, Cin=Cout=256, H=W=128, K=3, GROUPS=128
#define BATCH 8
#define CH    256
#define HH    128
#define WW    128
#define HW    (HH*WW)          // 16384
#define NGRP  128
#define CPG   2                // channels per group (in and out)
#define EPS   1e-7f

// ---------------- Kernel 1: per-(b,c) mean / rstd ----------------
// One block per channel. 256 threads, float4 loads: 16384 floats = 4096 float4.
__global__ __launch_bounds__(256) void stats_kernel(
    const float* __restrict__ x, float* __restrict__ mean_o, float* __restrict__ rstd_o)
{
    const int c = blockIdx.x;                       // 0..2047 = b*256+c
    const float4* p = (const float4*)(x + (size_t)c * HW);
    float s = 0.f, ss = 0.f;
    for (int i = threadIdx.x; i < HW/4; i += 256) {
        float4 v = p[i];
        s  += v.x + v.y + v.z + v.w;
        ss += v.x*v.x + v.y*v.y + v.z*v.z + v.w*v.w;
    }
    // wave64 butterfly
    #pragma unroll
    for (int off = 32; off > 0; off >>= 1) {
        s  += __shfl_down(s,  off);
        ss += __shfl_down(ss, off);
    }
    __shared__ float ls[4], lss[4];
    const int wave = threadIdx.x >> 6;
    if ((threadIdx.x & 63) == 0) { ls[wave] = s; lss[wave] = ss; }
    __syncthreads();
    if (threadIdx.x == 0) {
        s  = ls[0]  + ls[1]  + ls[2]  + ls[3];
        ss = lss[0] + lss[1] + lss[2] + lss[3];
        const float m   = s * (1.0f / (float)HW);
        float var = (ss - s * m) * (1.0f / (float)(HW - 1));   // Bessel (N-1)
        var = fmaxf(var, 0.0f);
        const float sd = sqrtf(var) + EPS;                     // std = sqrt(var)+eps (ref)
        mean_o[c] = m;
        rstd_o[c] = 1.0f / sd;
    }
}

// ---------------- Kernel 2: fused normalize + grouped 3x3 + grouped 1x1 + bias ----
// Tile: 16 rows x 64 cols. Block = 256 threads (4 row-groups x 64 cols).
// grid = (16 tiles, 128 groups, 8 batch)
#define TH 16
#define TW 64

__global__ __launch_bounds__(256) void adaconv_kernel(
    const float* __restrict__ x,
    const float* __restrict__ dwk,     // [B, 256, 2, 3, 3]
    const float* __restrict__ pwk,     // [B, 256, 2]
    const float* __restrict__ bias,    // [B, 256]
    const float* __restrict__ mean_i,  // [B*256]
    const float* __restrict__ rstd_i,  // [B*256]
    float* __restrict__ out)
{
    const int b  = blockIdx.z;
    const int g  = blockIdx.y;
    const int th0 = (blockIdx.x >> 1) * TH;   // 8 tiles vertically
    const int tw0 = (blockIdx.x & 1)  * TW;   // 2 tiles horizontally

    const int c0  = g * CPG;                  // first channel of this group
    const int bc0 = b * CH + c0;

    __shared__ float xs[CPG][TH + 2][TW + 2];   // 2*18*66*4 = 9504 B

    const float m0 = mean_i[bc0],     r0 = rstd_i[bc0];
    const float m1 = mean_i[bc0 + 1], r1 = rstd_i[bc0 + 1];
    const float* xb = x + (size_t)bc0 * HW;

    // cooperative load of the normalized halo tile (zero outside image)
    const int NE = CPG * (TH + 2) * (TW + 2);   // 2376
    for (int e = threadIdx.x; e < NE; e += 256) {
        const int c   = e / ((TH + 2) * (TW + 2));
        const int rem = e - c * ((TH + 2) * (TW + 2));
        const int r   = rem / (TW + 2);
        const int col = rem - r * (TW + 2);
        const int gh = th0 + r - 1;
        const int gw = tw0 + col - 1;
        float v = 0.0f;
        if (gh >= 0 && gh < HH && gw >= 0 && gw < WW) {
            v = xb[c * HW + gh * WW + gw];
            v = (v - (c ? m1 : m0)) * (c ? r1 : r0);
        }
        ((float*)xs)[e] = v;   // flat index == c*(18*66)+r*66+col
    }

    // weights for this (b, g): 2 out-ch x 2 in-ch x 9 taps (block-uniform)
    float wdw[2][2][9];
    #pragma unroll
    for (int co = 0; co < 2; ++co)
        #pragma unroll
        for (int ci = 0; ci < 2; ++ci)
            #pragma unroll
            for (int k = 0; k < 9; ++k)
                wdw[co][ci][k] = dwk[(((size_t)(bc0 + co)) * 2 + ci) * 9 + k];

    const float p00 = pwk[(size_t)(bc0 + 0) * 2 + 0];
    const float p01 = pwk[(size_t)(bc0 + 0) * 2 + 1];
    const float p10 = pwk[(size_t)(bc0 + 1) * 2 + 0];
    const float p11 = pwk[(size_t)(bc0 + 1) * 2 + 1];
    const float bb0 = bias[bc0], bb1 = bias[bc0 + 1];

    __syncthreads();

    const int tx = threadIdx.x & 63;     // column in tile
    const int rg = threadIdx.x >> 6;     // row group 0..3
    float* outb = out + (size_t)bc0 * HW;

    #pragma unroll
    for (int j = 0; j < 4; ++j) {
        const int r = rg * 4 + j;        // row in tile 0..15
        float d0 = 0.f, d1 = 0.f;
        #pragma unroll
        for (int ci = 0; ci < 2; ++ci) {
            #pragma unroll
            for (int ky = 0; ky < 3; ++ky) {
                #pragma unroll
                for (int kx = 0; kx < 3; ++kx) {
                    const float v = xs[ci][r + ky][tx + kx];
                    d0 = fmaf(v, wdw[0][ci][ky * 3 + kx], d0);
                    d1 = fmaf(v, wdw[1][ci][ky * 3 + kx], d1);
                }
            }
        }
        const int gh = th0 + r;
        const int gw = tw0 + tx;
        outb[gh * WW + gw]      = fmaf(p00, d0, fmaf(p01, d1, bb0));
        outb[HW + gh * WW + gw] = fmaf(p10, d0, fmaf(p11, d1, bb1));
    }
}

extern "C" void kernel_launch(void* const* d_in, const int* in_sizes, int n_in,
                              void* d_out, int out_size, void* d_ws, size_t ws_size,
                              hipStream_t stream)
{
    const float* x    = (const float*)d_in[0];   // [8,256,128,128]
    const float* dwk  = (const float*)d_in[1];   // [8,256,2,3,3]
    const float* pwk  = (const float*)d_in[2];   // [8,256,2,1,1]
    const float* bias = (const float*)d_in[3];   // [8,256]
    float* out  = (float*)d_out;                 // [8,256,128,128]

    float* mean_b = (float*)d_ws;                // 2048 floats
    float* rstd_b = mean_b + BATCH * CH;         // 2048 floats

    stats_kernel<<<BATCH * CH, 256, 0, stream>>>(x, mean_b, rstd_b);

    dim3 grid((HH / TH) * (WW / TW), NGRP, BATCH);   // (16, 128, 8)
    adaconv_kernel<<<grid, 256, 0, stream>>>(x, dwk, pwk, bias, mean_b, rstd_b, out);
}

// Round 2
// 274.792 us; speedup vs baseline: 1.0266x; 1.0266x over previous
//
#include <hip/hip_runtime.h>
#include <math.h>

// Problem constants: B=8, Cin=Cout=256, H=W=128, K=3, GROUPS=128
#define BATCH 8
#define CH    256
#define HH    128
#define WW    128
#define HW    (HH*WW)          // 16384
#define NGRP  128
#define CPG   2
#define EPS   1e-7f

// ---------------- Kernel 1: per-(b,c) mean / rstd ----------------
__global__ __launch_bounds__(256) void stats_kernel(
    const float* __restrict__ x, float* __restrict__ mean_o, float* __restrict__ rstd_o)
{
    const int c = blockIdx.x;                       // 0..2047 = b*256+c
    const float4* p = (const float4*)(x + (size_t)c * HW);
    float s = 0.f, ss = 0.f;
    #pragma unroll 4
    for (int i = threadIdx.x; i < HW/4; i += 256) {
        float4 v = p[i];
        s  += v.x + v.y + v.z + v.w;
        ss += v.x*v.x + v.y*v.y + v.z*v.z + v.w*v.w;
    }
    #pragma unroll
    for (int off = 32; off > 0; off >>= 1) {
        s  += __shfl_down(s,  off);
        ss += __shfl_down(ss, off);
    }
    __shared__ float ls[4], lss[4];
    const int wave = threadIdx.x >> 6;
    if ((threadIdx.x & 63) == 0) { ls[wave] = s; lss[wave] = ss; }
    __syncthreads();
    if (threadIdx.x == 0) {
        s  = ls[0]  + ls[1]  + ls[2]  + ls[3];
        ss = lss[0] + lss[1] + lss[2] + lss[3];
        const float m = s * (1.0f / (float)HW);
        float var = (ss - s * m) * (1.0f / (float)(HW - 1));   // Bessel (N-1)
        var = fmaxf(var, 0.0f);
        const float sd = sqrtf(var) + EPS;                     // std = sqrt(var)+eps
        mean_o[c] = m;
        rstd_o[c] = 1.0f / sd;
    }
}

// ---------------- Kernel 2: fused normalize + grouped 3x3 (+folded 1x1) + bias ----
// Tile: 16 rows x 128 cols (full width -> horizontal halo is pure zero).
// Block 256 threads: thread t -> cols 4*(t&31).., output rows 2*(t>>5)..+1, both channels.
// grid = (8 vtiles, 128 groups, 8 batch)
#define TH 16
#define XSS 136     // LDS row stride in floats (136*4=544 B, 16B-aligned rows)
// image col gw maps to xs col gw+4 ; gw=-1 -> col 3 ; gw=128 -> col 132 (both zeroed)

__global__ __launch_bounds__(256) void adaconv_kernel(
    const float* __restrict__ x,
    const float* __restrict__ dwk,     // [B, 256, 2, 3, 3]
    const float* __restrict__ pwk,     // [B, 256, 2]
    const float* __restrict__ bias,    // [B, 256]
    const float* __restrict__ mean_i,  // [B*256]
    const float* __restrict__ rstd_i,  // [B*256]
    float* __restrict__ out)
{
    const int b   = blockIdx.z;
    const int g   = blockIdx.y;
    const int th0 = blockIdx.x * TH;
    const int bc0 = b * CH + g * CPG;
    const int tid = threadIdx.x;

    __shared__ float xs[CPG][TH + 2][XSS];   // 2*18*136*4 = 19584 B

    const float r0s = rstd_i[bc0],     m0 = mean_i[bc0];
    const float r1s = rstd_i[bc0 + 1], m1 = mean_i[bc0 + 1];
    const float nm0 = -m0 * r0s, nm1 = -m1 * r1s;
    const float* xb = x + (size_t)bc0 * HW;

    // zero the K=3 horizontal halo columns (gw=-1 -> col 3, gw=128 -> col 132)
    if (tid < CPG * (TH + 2)) {              // 36 threads
        const int ci  = tid / (TH + 2);
        const int row = tid - ci * (TH + 2);
        xs[ci][row][3]   = 0.f;
        xs[ci][row][132] = 0.f;
    }

    // staging: 2 ch * 18 rows * 32 float4 = 1152 vector loads, normalized on the fly
    for (int e = tid; e < CPG * (TH + 2) * 32; e += 256) {
        const int ci  = e / ((TH + 2) * 32);
        const int rem = e - ci * ((TH + 2) * 32);
        const int row = rem >> 5;
        const int c4  = rem & 31;
        const int gh  = th0 + row - 1;
        float4 v = make_float4(0.f, 0.f, 0.f, 0.f);
        if (gh >= 0 && gh < HH) {
            v = *(const float4*)(xb + (size_t)ci * HW + gh * WW + (c4 << 2));
            const float sc = ci ? r1s : r0s;
            const float ad = ci ? nm1 : nm0;
            v.x = fmaf(v.x, sc, ad); v.y = fmaf(v.y, sc, ad);
            v.z = fmaf(v.z, sc, ad); v.w = fmaf(v.w, sc, ad);
        }
        *(float4*)&xs[ci][row][4 + (c4 << 2)] = v;
    }

    // effective 3x3 weights with the 1x1 pointwise folded in:
    // we[o][ci][k] = pw[o][0]*dw[0][ci][k] + pw[o][1]*dw[1][ci][k]
    const float p00 = pwk[(size_t)(bc0 + 0) * 2 + 0];
    const float p01 = pwk[(size_t)(bc0 + 0) * 2 + 1];
    const float p10 = pwk[(size_t)(bc0 + 1) * 2 + 0];
    const float p11 = pwk[(size_t)(bc0 + 1) * 2 + 1];
    const float* dwb = dwk + (size_t)bc0 * 18;   // [outch][ci][k], ch stride 18
    float we[2][2][9];
    #pragma unroll
    for (int ci = 0; ci < 2; ++ci)
        #pragma unroll
        for (int k = 0; k < 9; ++k) {
            const float w0 = dwb[ci * 9 + k];        // out-ch 0
            const float w1 = dwb[18 + ci * 9 + k];   // out-ch 1
            we[0][ci][k] = fmaf(p00, w0, p01 * w1);
            we[1][ci][k] = fmaf(p10, w0, p11 * w1);
        }
    const float bb0 = bias[bc0], bb1 = bias[bc0 + 1];

    __syncthreads();

    const int c0    = (tid & 31) << 2;   // first of 4 output cols
    const int rbase = (tid >> 5) << 1;   // first of 2 output rows (tile-local)

    float acc[2][2][4];                  // [outrow][outch][col]
    #pragma unroll
    for (int o = 0; o < 2; ++o)
        #pragma unroll
        for (int cc = 0; cc < 4; ++cc) { acc[o][0][cc] = bb0; acc[o][1][cc] = bb1; }

    #pragma unroll
    for (int r = 0; r < 4; ++r) {
        #pragma unroll
        for (int ci = 0; ci < 2; ++ci) {
            const float* rowp = &xs[ci][rbase + r][0];
            const float2 L = *(const float2*)(rowp + c0 + 2);   // image cols c0-2,c0-1
            const float4 M = *(const float4*)(rowp + c0 + 4);   // image cols c0..c0+3
            const float2 R = *(const float2*)(rowp + c0 + 8);   // image cols c0+4,c0+5
            const float xv[6] = { L.y, M.x, M.y, M.z, M.w, R.x }; // cols c0-1..c0+4
            #pragma unroll
            for (int o = 0; o < 2; ++o) {
                const int ky = r - o;
                if (ky < 0 || ky > 2) continue;
                #pragma unroll
                for (int ch = 0; ch < 2; ++ch)
                    #pragma unroll
                    for (int cc = 0; cc < 4; ++cc)
                        #pragma unroll
                        for (int kx = 0; kx < 3; ++kx)
                            acc[o][ch][cc] = fmaf(we[ch][ci][ky * 3 + kx],
                                                  xv[cc + kx], acc[o][ch][cc]);
            }
        }
    }

    float* outb = out + (size_t)bc0 * HW;
    #pragma unroll
    for (int o = 0; o < 2; ++o) {
        const int gr = th0 + rbase + o;
        #pragma unroll
        for (int ch = 0; ch < 2; ++ch) {
            const float4 vv = make_float4(acc[o][ch][0], acc[o][ch][1],
                                          acc[o][ch][2], acc[o][ch][3]);
            *(float4*)(outb + (size_t)ch * HW + gr * WW + c0) = vv;
        }
    }
}

extern "C" void kernel_launch(void* const* d_in, const int* in_sizes, int n_in,
                              void* d_out, int out_size, void* d_ws, size_t ws_size,
                              hipStream_t stream)
{
    const float* x    = (const float*)d_in[0];   // [8,256,128,128]
    const float* dwk  = (const float*)d_in[1];   // [8,256,2,3,3]
    const float* pwk  = (const float*)d_in[2];   // [8,256,2,1,1]
    const float* bias = (const float*)d_in[3];   // [8,256]
    float* out = (float*)d_out;                  // [8,256,128,128]

    float* mean_b = (float*)d_ws;                // 2048 floats
    float* rstd_b = mean_b + BATCH * CH;         // 2048 floats

    stats_kernel<<<BATCH * CH, 256, 0, stream>>>(x, mean_b, rstd_b);

    dim3 grid(HH / TH, NGRP, BATCH);             // (8, 128, 8)
    adaconv_kernel<<<grid, 256, 0, stream>>>(x, dwk, pwk, bias, mean_b, rstd_b, out);
}

// Round 3
// 251.733 us; speedup vs baseline: 1.1206x; 1.0916x over previous
//
#include <hip/hip_runtime.h>
#include <math.h>

// Problem constants: B=8, Cin=Cout=256, H=W=128, K=3, GROUPS=128 (2 ch/group)
#define BATCH 8
#define CH    256
#define HH    128
#define WW    128
#define HW    (HH*WW)          // 16384
#define NGRP  128
#define EPS   1e-7f
#define XSS   136              // LDS row stride in floats (544 B, 16B-aligned)

// Fully fused: per-block (b,g) -> stage raw 2 channels to LDS + stats +
// normalization folded into weights/bias + halo=mean trick + 3x3 (+1x1) conv.
// Image col gw maps to xs col gw+4; gw=-1 -> col 3; gw=128 -> col 132.
// Image row gh maps to xs row gh+1; rows 0 and 129 are the vertical halo.
__global__ __launch_bounds__(512) void fused_adaconv_kernel(
    const float* __restrict__ x,      // [8,256,128,128]
    const float* __restrict__ dwk,    // [8,256,2,3,3]
    const float* __restrict__ pwk,    // [8,256,2]
    const float* __restrict__ bias,   // [8,256]
    float* __restrict__ out)          // [8,256,128,128]
{
    const int g   = blockIdx.x;           // 0..127
    const int b   = blockIdx.y;           // 0..7
    const int bc0 = b * CH + g * 2;
    const int tid = threadIdx.x;

    __shared__ float xs[2][HH + 2][XSS];  // 141,440 B raw (then halo=m)
    __shared__ float red[16];             // 8 wave partials x {s,ss}
    __shared__ float stat[4];             // m0, r0, m1, r1

    const float* xb = x + (size_t)bc0 * HW;

    // ---- stage raw x -> LDS (float4), accumulate s/ss in registers ----
    // 256 threads per channel; thread covers 16 float4 (64 elems).
    const int ci = tid >> 8;              // waves 0-3 -> ch0, waves 4-7 -> ch1
    const int tl = tid & 255;
    const float4* src = (const float4*)(xb + (size_t)ci * HW);
    float s = 0.f, ss = 0.f;
    #pragma unroll
    for (int k = 0; k < 16; ++k) {
        const int f = (k << 8) + tl;      // float4 index 0..4095 (coalesced)
        float4 v = src[f];
        s  += v.x + v.y + v.z + v.w;
        ss += v.x*v.x + v.y*v.y + v.z*v.z + v.w*v.w;
        *(float4*)&xs[ci][(f >> 5) + 1][4 + ((f & 31) << 2)] = v;
    }

    // ---- block reduction -> per-channel mean / rstd ----
    #pragma unroll
    for (int off = 32; off; off >>= 1) {
        s  += __shfl_down(s,  off);
        ss += __shfl_down(ss, off);
    }
    const int wv = tid >> 6;
    if ((tid & 63) == 0) { red[wv] = s; red[8 + wv] = ss; }
    __syncthreads();
    if (tid < 2) {
        const int base = tid * 4;
        const float S  = red[base] + red[base+1] + red[base+2] + red[base+3];
        const float SS = red[8+base] + red[9+base] + red[10+base] + red[11+base];
        const float m  = S * (1.0f / (float)HW);
        float var = (SS - S * m) * (1.0f / (float)(HW - 1));   // Bessel (N-1)
        var = fmaxf(var, 0.0f);
        stat[tid * 2]     = m;
        stat[tid * 2 + 1] = 1.0f / (sqrtf(var) + EPS);         // 1/(std+eps)
    }
    __syncthreads();
    const float m0 = stat[0], r0 = stat[1], m1 = stat[2], r1 = stat[3];

    // ---- halo := channel mean  ->  (m - m)*r = 0 == reference zero-pad ----
    // per ci: rows 0 & 129 (136 cols each) + cols 3 & 132 (rows 1..128) = 528
    for (int e = tid; e < 1056; e += 512) {
        const int c  = (e >= 528);
        const int i  = c ? (e - 528) : e;
        const float mv = c ? m1 : m0;
        if (i < 272) {
            const int row = (i < 136) ? 0 : (HH + 1);
            const int col = (i < 136) ? i : (i - 136);
            xs[c][row][col] = mv;
        } else {
            const int r2  = i - 272;           // 0..255
            const int row = 1 + (r2 & 127);
            const int col = (r2 < 128) ? 3 : 132;
            xs[c][row][col] = mv;
        }
    }

    // ---- fold pointwise + rstd into 3x3 weights; fold mean into bias ----
    const float p00 = pwk[(size_t)bc0 * 2 + 0];
    const float p01 = pwk[(size_t)bc0 * 2 + 1];
    const float p10 = pwk[(size_t)bc0 * 2 + 2];
    const float p11 = pwk[(size_t)bc0 * 2 + 3];
    const float* dwb = dwk + (size_t)bc0 * 18;   // [outch][ci][9]
    float we[2][2][9];
    float bb[2] = { bias[bc0], bias[bc0 + 1] };
    #pragma unroll
    for (int cc = 0; cc < 2; ++cc) {
        const float rr = cc ? r1 : r0;
        const float mm = cc ? m1 : m0;
        #pragma unroll
        for (int k = 0; k < 9; ++k) {
            const float w0 = dwb[cc * 9 + k];        // depthwise out-ch 0
            const float w1 = dwb[18 + cc * 9 + k];   // depthwise out-ch 1
            const float e0 = fmaf(p00, w0, p01 * w1) * rr;
            const float e1 = fmaf(p10, w0, p11 * w1) * rr;
            we[0][cc][k] = e0;
            we[1][cc][k] = e1;
            bb[0] -= mm * e0;
            bb[1] -= mm * e1;
        }
    }
    __syncthreads();   // halo writes visible before conv reads

    // ---- conv: thread -> 4 cols x 8 rows x 2 out-ch (two 4-row chunks) ----
    const int c0  = (tid & 31) << 2;      // output cols c0..c0+3
    const int rb0 = (tid >> 5) << 3;      // output rows rb0..rb0+7
    float* outb = out + (size_t)bc0 * HW;

    #pragma unroll
    for (int hc = 0; hc < 2; ++hc) {
        const int rb = rb0 + hc * 4;      // first output row of chunk
        float acc[4][2][4];               // [row j][outch][col]
        #pragma unroll
        for (int j = 0; j < 4; ++j)
            #pragma unroll
            for (int q = 0; q < 4; ++q) { acc[j][0][q] = bb[0]; acc[j][1][q] = bb[1]; }

        #pragma unroll
        for (int xr = 0; xr < 6; ++xr) {          // xs rows rb..rb+5
            #pragma unroll
            for (int cin = 0; cin < 2; ++cin) {
                const float* rowp = &xs[cin][rb + xr][0];
                const float2 L = *(const float2*)(rowp + c0 + 2);  // img col c0-2,c0-1
                const float4 M = *(const float4*)(rowp + c0 + 4);  // img col c0..c0+3
                const float2 R = *(const float2*)(rowp + c0 + 8);  // img col c0+4,c0+5
                const float xv[6] = { L.y, M.x, M.y, M.z, M.w, R.x };
                #pragma unroll
                for (int j = 0; j < 4; ++j) {
                    const int ky = xr - j;        // tap row
                    if (ky < 0 || ky > 2) continue;
                    #pragma unroll
                    for (int ch = 0; ch < 2; ++ch)
                        #pragma unroll
                        for (int q = 0; q < 4; ++q)
                            #pragma unroll
                            for (int kx = 0; kx < 3; ++kx)
                                acc[j][ch][q] = fmaf(we[ch][cin][ky * 3 + kx],
                                                     xv[q + kx], acc[j][ch][q]);
                }
            }
        }

        #pragma unroll
        for (int j = 0; j < 4; ++j) {
            const int gr = rb + j;
            #pragma unroll
            for (int ch = 0; ch < 2; ++ch) {
                const float4 vv = make_float4(acc[j][ch][0], acc[j][ch][1],
                                              acc[j][ch][2], acc[j][ch][3]);
                *(float4*)(outb + (size_t)ch * HW + gr * WW + c0) = vv;
            }
        }
    }
}

extern "C" void kernel_launch(void* const* d_in, const int* in_sizes, int n_in,
                              void* d_out, int out_size, void* d_ws, size_t ws_size,
                              hipStream_t stream)
{
    const float* x    = (const float*)d_in[0];   // [8,256,128,128]
    const float* dwk  = (const float*)d_in[1];   // [8,256,2,3,3]
    const float* pwk  = (const float*)d_in[2];   // [8,256,2,1,1]
    const float* bias = (const float*)d_in[3];   // [8,256]
    float* out = (float*)d_out;                  // [8,256,128,128]

    dim3 grid(NGRP, BATCH);                      // 1024 blocks, one per (b,g)
    fused_adaconv_kernel<<<grid, 512, 0, stream>>>(x, dwk, pwk, bias, out);
}